// Round 8
// baseline (489.506 us; speedup 1.0000x reference)
//
#include <hip/hip_runtime.h>

// Monarch block-diag: out[b, s*64+l] = sum_r w2[l,s,r] * sum_p x[b, r*64+p] * w1[r,l,p]
// B=8192, N=4096, blocks 64. fp32 in/out; bf16 MFMA compute.
//
// R8: r0-r7 established the write law: a 256-B out granule (out[b][s*64..+64]) is
// amplification-free ONLY when one store INSTRUCTION covers it entirely (r4: 16 adjacent
// lanes x dwordx4 -> 1.07x ideal; per-instruction-scattered variants -> 1.85-2.1x even
// when one lane/wave completes the granule back-to-back -- r7). So:
//   - stage-2 consumes Y fully into registers (acc2[64]/lane, lane owns one granule),
//     allowing the O epilogue buffer (64 KiB) to ALIAS Y (64 KiB) -> 2 blocks/CU for
//     phase overlap (r4's 1-block serialization capped BW at 2.1 TB/s).
//   - epilogue: 2 rounds by s-half; writer waves dump acc2 -> O[b][sl][l]; all threads
//     then store 16-lane x dwordx4 = one aligned 256-B granule per instruction.
//   - NEW swizzle phys = kc ^ (q&7) ^ ((2*bl)&7): r7's (bl&7) variant left only 4
//     bank-groups for 16 addrs in stage-2 reads (4-way conflict, 4.19M events); the
//     2*bl term injects bit2 -> all 8 groups, 2 dwords/bank = minimum. Verified for
//     stage-1 writes, both stage-2 frags, O-write (l4^(sl&7)), O-read.

typedef __bf16 bf16x8 __attribute__((ext_vector_type(8)));
typedef float  float4v __attribute__((ext_vector_type(4)));

__global__ __launch_bounds__(256)
void cvt_weights(const float* __restrict__ w1, const float* __restrict__ w2,
                 __bf16* __restrict__ wb) {
    const int i = (blockIdx.x * 256 + threadIdx.x) * 8;  // grid 128 -> i < 262144
    float4v a = *(const float4v*)(w1 + i);
    float4v b = *(const float4v*)(w1 + i + 4);
    bf16x8 v;
    v[0]=(__bf16)a[0]; v[1]=(__bf16)a[1]; v[2]=(__bf16)a[2]; v[3]=(__bf16)a[3];
    v[4]=(__bf16)b[0]; v[5]=(__bf16)b[1]; v[6]=(__bf16)b[2]; v[7]=(__bf16)b[3];
    *(bf16x8*)(wb + i) = v;
    a = *(const float4v*)(w2 + i);
    b = *(const float4v*)(w2 + i + 4);
    v[0]=(__bf16)a[0]; v[1]=(__bf16)a[1]; v[2]=(__bf16)a[2]; v[3]=(__bf16)a[3];
    v[4]=(__bf16)b[0]; v[5]=(__bf16)b[1]; v[6]=(__bf16)b[2]; v[7]=(__bf16)b[3];
    *(bf16x8*)(wb + 262144 + i) = v;
}

__global__ __launch_bounds__(512, 4)
void monarch_fused(const float* __restrict__ x,
                   const __bf16* __restrict__ w1b,
                   const __bf16* __restrict__ w2b,
                   float* __restrict__ out)
{
    // Y: [bl(8)][q(64)][kslot(8) swz][elem(8)] bf16 = 64 KiB; swz = kc ^ (q&7) ^ ((2bl)&7).
    // O: [b(8)][sl(32)][l-slot(16) swz][li(4)] fp32 = 64 KiB, aliases Y post-consumption.
    extern __shared__ __align__(16) unsigned char smem[];
    __bf16* Y = (__bf16*)smem;
    float*  O = (float*)smem;

    const int tid  = threadIdx.x;
    const int wid  = tid >> 6;      // 0..7
    const int lane = tid & 63;
    const int m    = lane & 15;
    const int quad = lane >> 4;
    const int b0   = blockIdx.x * 8;
    const int brow = m & 7;         // stage-1 real b-row (A rows 8..15 duplicate)

    // ---- stage-1: wave = k-chunk kw; preload x A-frags (k = kw*8+j, p = h*32+quad*8+e)
    const int kw = wid;
    bf16x8 xa[8][2];
    {
        const float* xp = x + (long)(b0 + brow) * 4096 + kw * 512 + quad * 8;
        #pragma unroll
        for (int j = 0; j < 8; ++j) {
            #pragma unroll
            for (int h = 0; h < 2; ++h) {
                float4v lo = *(const float4v*)(xp + j * 64 + h * 32);
                float4v hi = *(const float4v*)(xp + j * 64 + h * 32 + 4);
                bf16x8 v;
                v[0]=(__bf16)lo[0]; v[1]=(__bf16)lo[1]; v[2]=(__bf16)lo[2]; v[3]=(__bf16)lo[3];
                v[4]=(__bf16)hi[0]; v[5]=(__bf16)hi[1]; v[6]=(__bf16)hi[2]; v[7]=(__bf16)hi[3];
                xa[j][h] = v;
            }
        }
    }

    // ---- stage-1 compute: Y[b][q][k] for k in [kw*8,+8), all 64 q (4 tiles) ----
    #pragma unroll
    for (int qt = 0; qt < 4; ++qt) {
        float4v acc[8];
        #pragma unroll
        for (int j = 0; j < 8; ++j) {
            const int k = kw * 8 + j;
            const __bf16* w1p = w1b + ((k * 64 + qt * 16 + m) * 64) + quad * 8;
            bf16x8 bb0 = *(const bf16x8*)(w1p);
            bf16x8 bb1 = *(const bf16x8*)(w1p + 32);
            float4v c = {0.f, 0.f, 0.f, 0.f};
            c = __builtin_amdgcn_mfma_f32_16x16x32_bf16(xa[j][0], bb0, c, 0, 0, 0);
            c = __builtin_amdgcn_mfma_f32_16x16x32_bf16(xa[j][1], bb1, c, 0, 0, 0);
            acc[j] = c;
        }
        // D: lane holds D[b = quad*4+reg][q = qt*16+m]; rows >=8 are duplicates -> skip.
        if (quad < 2) {
            #pragma unroll
            for (int reg = 0; reg < 4; ++reg) {
                const int bl = quad * 4 + reg;        // 0..7
                const int q  = qt * 16 + m;
                const int cs = kw ^ (m & 7) ^ ((2 * bl) & 7);
                bf16x8 v;
                #pragma unroll
                for (int j = 0; j < 8; ++j) v[j] = (__bf16)acc[j][reg];
                *(bf16x8*)(&Y[((bl * 64 + q) * 8 + cs) * 8]) = v;
            }
        }
    }
    __syncthreads();  // Y complete

    // ---- stage-2: wave = (st = wid>>1, bh = wid&1). A = w2 (M=s), B = Y (N=b dup x4).
    // Lane keeps D[row = quad*4 + sreg][col = m] => b = bh*4+(m&3),
    // s = st*16 + quad*4 + sreg (sreg = m>>2); acc2[l] over all 64 l = one granule.
    const int st   = wid >> 1;
    const int bh   = wid & 1;
    const int bcol = bh * 4 + (m & 3);
    const int sreg = m >> 2;
    const int sl   = (st & 1) * 16 + quad * 4 + sreg;   // s = (st>>1)*32 + sl

    const __bf16* w2base = w2b + (st * 16 + m) * 64 + quad * 8;
    const __bf16* Ybase  = Y + bcol * 64 * 64;   // Y[bcol][.][.]

    float acc2[64];
    #pragma unroll
    for (int l = 0; l < 64; ++l) {
        // A-frag: w2[l][s = st*16+m][r = kc*8 + e], kc = quad / quad+4
        const __bf16* w2p = w2base + l * 4096;
        bf16x8 af0 = *(const bf16x8*)(w2p);
        bf16x8 af1 = *(const bf16x8*)(w2p + 32);
        // B-frag: Y[bcol][l][r] (4-way col dup broadcasts); slot swz = kc^(l&7)^((2bcol)&7)
        const int cs0 = quad ^ (l & 7) ^ ((2 * bcol) & 7);
        bf16x8 bf0 = *(const bf16x8*)(&Ybase[(l * 8 + cs0) * 8]);
        bf16x8 bf1 = *(const bf16x8*)(&Ybase[(l * 8 + (cs0 ^ 4)) * 8]);
        float4v c = {0.f, 0.f, 0.f, 0.f};
        c = __builtin_amdgcn_mfma_f32_16x16x32_bf16(af0, bf0, c, 0, 0, 0);
        c = __builtin_amdgcn_mfma_f32_16x16x32_bf16(af1, bf1, c, 0, 0, 0);
        acc2[l] = (sreg == 0) ? c[0] : (sreg == 1) ? c[1] : (sreg == 2) ? c[2] : c[3];
    }
    __syncthreads();  // Y fully consumed by ALL waves -> O may overwrite

    // ---- epilogue: 2 rounds by s-half h. O dword addr = (b*32+sl)*64 + (l4^(sl&7))*4.
    // Write: waves with st>>1 == h (4 waves); 64 distinct addrs/instr, 8 dw/bank (min).
    // Read+store: 8 iters x 512 thr; 16 adjacent lanes = one aligned 256-B granule
    // out[b][s*64..+64] per instruction (the r4-proven amplification-free pattern);
    // per wave-instr: 4 consecutive sl -> 1 KiB contiguous HBM.
    #pragma unroll
    for (int h = 0; h < 2; ++h) {
        if (h) __syncthreads();  // round-0 O reads done before round-1 overwrites

        if ((st >> 1) == h) {
            #pragma unroll
            for (int l4 = 0; l4 < 16; ++l4) {
                const int phys = l4 ^ (sl & 7);
                float4v v = { acc2[l4 * 4 + 0], acc2[l4 * 4 + 1],
                              acc2[l4 * 4 + 2], acc2[l4 * 4 + 3] };
                *(float4v*)(&O[((bcol * 32 + sl) << 6) + (phys << 2)]) = v;
            }
        }
        __syncthreads();

        const int f   = tid & 15;         // l-slot within granule
        const int slr = tid >> 4;         // 0..31 (wave w covers slr = 4w..4w+3)
        #pragma unroll
        for (int it = 0; it < 8; ++it) {  // it = b
            const int phys = f ^ (slr & 7);
            float4v v = *(const float4v*)(&O[((it * 32 + slr) << 6) + (phys << 2)]);
            float* dst = out + (long)(b0 + it) * 4096 + (h * 32 + slr) * 64 + f * 4;
            *(float4v*)dst = v;
        }
    }
}

extern "C" void kernel_launch(void* const* d_in, const int* in_sizes, int n_in,
                              void* d_out, int out_size, void* d_ws, size_t ws_size,
                              hipStream_t stream) {
    const float* x  = (const float*)d_in[0];
    const float* w1 = (const float*)d_in[1];
    const float* w2 = (const float*)d_in[2];
    float* out = (float*)d_out;
    __bf16* wb = (__bf16*)d_ws;   // w1b at [0, 262144), w2b at [262144, 524288)

    hipLaunchKernelGGL(cvt_weights, dim3(128), dim3(256), 0, stream, w1, w2, wb);
    hipLaunchKernelGGL(monarch_fused, dim3(8192 / 8), dim3(512), 65536, stream,
                       x, wb, wb + 262144, out);
}